// Round 17
// baseline (790.546 us; speedup 1.0000x reference)
//
#include <hip/hip_runtime.h>
#include <cstdint>
#include <cstddef>

// ---------------- problem constants ----------------
constexpr int BSZ = 32;
constexpr int T   = 1024;
constexpr int ID  = 256;
constexpr int MD  = 8;
constexpr int ORD = 256;
constexpr int HID = 512;
constexpr int BD  = BSZ * MD;   // 256
constexpr int CH  = 64;
constexpr int NQ  = T / CH;     // 16
constexpr int DO  = MD * ORD;   // 2048
constexpr int OO  = ORD * ORD;  // 65536
constexpr int KTOT24 = CH + ORD; // 320

typedef unsigned short ushort_t;
typedef __attribute__((ext_vector_type(8))) short bf16x8;
typedef __attribute__((ext_vector_type(8))) unsigned short us8;
typedef __attribute__((ext_vector_type(4))) float f32x4;

__device__ inline ushort_t f2bf(float f) {
    union { float f; uint32_t u; } v; v.f = f;
    uint32_t r = v.u + 0x7fffu + ((v.u >> 16) & 1u);
    return (ushort_t)(r >> 16);
}

__device__ inline void gl_lds16(const void* g, void* l) {
    __builtin_amdgcn_global_load_lds(
        (const __attribute__((address_space(1))) void*)g,
        (__attribute__((address_space(3))) void*)l, 16, 0, 0);
}

// ---------------- workspace layout (bytes) ----------------
constexpr size_t AL = 256;
constexpr size_t alup(size_t x) { return (x + AL - 1) & ~(AL - 1); }
constexpr size_t OFF_U2   = 0;                                          // f32 BD*T (dead after lend; reused A256/A512)
constexpr size_t OFF_P    = alup(OFF_U2   + (size_t)BD * T * 4);        // f32 CH*ORD
constexpr size_t OFF_APOW = alup(OFF_P    + (size_t)CH * ORD * 4);      // f32 (CH+1)*OO (slot 0 = A128)
constexpr size_t OFF_MQ   = alup(OFF_APOW + (size_t)(CH + 1) * OO * 4); // f32 NQ*BD*ORD (scan A)
constexpr size_t OFF_LEND = alup(OFF_MQ   + (size_t)NQ * BD * ORD * 4); // f32 NQ*BD*ORD (scan B)
constexpr size_t OFF_U2B  = alup(OFF_LEND + (size_t)NQ * BD * ORD * 4); // bf16 BD*T
constexpr size_t OFF_PTRB = alup(OFF_U2B  + (size_t)BD * T * 2);        // bf16 (CH*ORD)*CH
constexpr size_t OFF_APB  = alup(OFF_PTRB + (size_t)CH * ORD * CH * 2); // bf16 CH*ORD*ORD
constexpr size_t OFF_WHBT = alup(OFF_APB  + (size_t)CH * ORD * ORD * 2);// bf16 HID*DO
constexpr size_t OFF_MQB  = alup(OFF_WHBT + (size_t)HID * DO * 2);      // bf16 NQ*BD*ORD
constexpr size_t OFF_FLG  = alup(OFF_MQB  + (size_t)NQ * BD * ORD * 2); // u32[256]
constexpr size_t OFF_MBUF = alup(OFF_FLG  + 1024);                      // bf16 G*T*DO

// flag indices: mflag[e]=F[e] (e=1..64), pcount=F[65], lendcnt=F[66],
// af128=F[67], af256=F[68], af512=F[69], s0=F+70, s1=F+86, s2=F+102, s3=F+118
__device__ inline void gwait(uint32_t* f, uint32_t want) {
    if (threadIdx.x == 0) {
        while (__hip_atomic_load(f, __ATOMIC_ACQUIRE,
                                 __HIP_MEMORY_SCOPE_AGENT) < want)
            __builtin_amdgcn_s_sleep(4);
    }
    __syncthreads();
}
__device__ inline void gpost(uint32_t* f, uint32_t v) {
    __syncthreads();
    if (threadIdx.x == 0)
        __hip_atomic_fetch_add(f, v, __ATOMIC_RELEASE,
                               __HIP_MEMORY_SCOPE_AGENT);
}

// ====== fused prep0: k_u (0..1023) + copyAT (1024..1087) + whbt + P0/flags ==
__global__ __launch_bounds__(256) void k_prep0(const float* __restrict__ x,
                                               const float* __restrict__ kern,
                                               float* __restrict__ U2,
                                               ushort_t* __restrict__ U2b,
                                               const float* __restrict__ A,
                                               float* __restrict__ Apow,
                                               ushort_t* __restrict__ Apb,
                                               const float* __restrict__ Wh,
                                               ushort_t* __restrict__ Whbt,
                                               const float* __restrict__ Brow,
                                               float* __restrict__ P,
                                               uint32_t* __restrict__ F) {
    __shared__ __align__(16) char sm[32 * (ID + 1) * 4 + ID * MD * 4];
    const int bid = blockIdx.x;
    const int tid = threadIdx.x;

    if (bid < 1024) {                      // ---- U2 projection ----
        float (*xs)[ID + 1] = (float (*)[ID + 1])sm;
        float (*ks)[MD]     = (float (*)[MD])(sm + 32 * (ID + 1) * 4);
        const int b  = bid / (T / 32);
        const int t0 = (bid % (T / 32)) * 32;
        for (int i = tid; i < ID * MD; i += 256) ks[i / MD][i % MD] = kern[i];
        const float* xp = x + ((size_t)b * T + t0) * ID;
        for (int i = tid; i < (32 * ID) / 4; i += 256) {
            float4 v = ((const float4*)xp)[i];
            int r = i >> 6, c = (i & 63) * 4;
            xs[r][c] = v.x; xs[r][c + 1] = v.y; xs[r][c + 2] = v.z; xs[r][c + 3] = v.w;
        }
        __syncthreads();
        const int d  = tid / 32;
        const int tl = tid % 32;
        float acc = 0.f;
        #pragma unroll 8
        for (int i = 0; i < ID; ++i) acc += xs[tl][i] * ks[i][d];
        size_t idx = ((size_t)b * MD + d) * T + t0 + tl;
        U2[idx]  = acc;
        U2b[idx] = f2bf(acc);
    } else if (bid < 1088) {               // ---- A -> Apow[1] + Apb[0]^T ----
        float (*t)[33] = (float (*)[33])sm;
        const int i2 = bid - 1024;
        const int o0 = (i2 & 7) * 32, p0 = (i2 >> 3) * 32;
        const int tx = tid & 31, ty = tid >> 5;
        #pragma unroll
        for (int p = 0; p < 4; ++p) {
            int r = ty + p * 8;
            float v = A[(size_t)(p0 + r) * ORD + o0 + tx];
            Apow[OO + (size_t)(p0 + r) * ORD + o0 + tx] = v;
            t[r][tx] = v;
        }
        __syncthreads();
        #pragma unroll
        for (int p = 0; p < 4; ++p) {
            int r = ty + p * 8;
            Apb[(size_t)(o0 + r) * ORD + p0 + tx] = f2bf(t[tx][r]);
        }
    } else if (bid < 2112) {               // ---- Whbt transpose ----
        float (*t)[33] = (float (*)[33])sm;
        const int i2 = bid - 1088;
        const int k0 = (i2 & 63) * 32, h0 = (i2 >> 6) * 32;
        const int tx = tid & 31, ty = tid >> 5;
        #pragma unroll
        for (int p = 0; p < 4; ++p) {
            int r = ty + p * 8;
            t[r][tx] = Wh[(size_t)(k0 + r) * HID + h0 + tx];
        }
        __syncthreads();
        #pragma unroll
        for (int p = 0; p < 4; ++p) {
            int r = ty + p * 8;
            Whbt[(size_t)(h0 + r) * DO + k0 + tx] = f2bf(t[tx][r]);
        }
    } else {                               // ---- P[0] = Brow + flag init ----
        F[tid] = 0u;
        __syncthreads();
        if (tid == 0) { F[1] = 16u; F[65] = 1u; }
        P[tid] = Brow[tid];
    }
}

// ============== mid-section unit bodies (K=128 staged, float4) =============
// pow sm: As f32[64][132] @0, Bs f32[128][68] @33792, tr ushort[64][72] @68608

__device__ void pow_unit(char* sm, int z, int ry, int cx, int tid,
                         float* Apow, ushort_t* Apb, int n) {
    float (*As)[132] = (float (*)[132])sm;
    float (*Bs)[68]  = (float (*)[68])(sm + 33792);
    ushort_t (*tr)[72] = (ushort_t (*)[72])(sm + 68608);
    const int row0 = ry * 64, col0 = cx * 64;
    const int tx = tid & 15, ty = tid >> 4;
    const float* Ag = Apow + (size_t)(z + 1) * OO;
    const float* Bg = Apow + (size_t)n * OO;
    float*       Cg = Apow + (size_t)(n + z + 1) * OO;

    float acc[4][4] = {};
    for (int k0 = 0; k0 < ORD; k0 += 128) {
        for (int i = tid; i < 64 * 32; i += 256) {
            int m = i >> 5, kv = (i & 31) * 4;
            *(float4*)&As[m][kv] =
                *(const float4*)&Ag[(size_t)(row0 + m) * ORD + k0 + kv];
        }
        for (int i = tid; i < 128 * 16; i += 256) {
            int kk = i >> 4, nv = (i & 15) * 4;
            *(float4*)&Bs[kk][nv] =
                *(const float4*)&Bg[(size_t)(k0 + kk) * ORD + col0 + nv];
        }
        __syncthreads();
        for (int kk = 0; kk < 128; ++kk) {
            float a[4], b[4];
            #pragma unroll
            for (int i = 0; i < 4; ++i) a[i] = As[ty * 4 + i][kk];
            #pragma unroll
            for (int j = 0; j < 4; ++j) b[j] = Bs[kk][tx * 4 + j];
            #pragma unroll
            for (int i = 0; i < 4; ++i)
                #pragma unroll
                for (int j = 0; j < 4; ++j) acc[i][j] += a[i] * b[j];
        }
        __syncthreads();
    }
    ushort_t* ap = Apb + (size_t)(n + z) * OO;
    #pragma unroll
    for (int i = 0; i < 4; ++i) {
        float4 v = make_float4(acc[i][0], acc[i][1], acc[i][2], acc[i][3]);
        *(float4*)&Cg[(size_t)(row0 + ty * 4 + i) * ORD + col0 + tx * 4] = v;
        #pragma unroll
        for (int j = 0; j < 4; ++j)
            tr[tx * 4 + j][ty * 4 + i] = f2bf(acc[i][j]);
    }
    __syncthreads();
    #pragma unroll
    for (int i = 0; i < 2; ++i) {
        int u = tid + i * 256;
        int cc = u >> 3, seg = (u & 7) * 8;
        *(us8*)&ap[(size_t)(col0 + cc) * ORD + row0 + seg] =
            *(const us8*)&tr[cc][seg];
    }
}

// P[n+j] = P[j] @ A^n
__device__ void p_double(char* sm, int j, int n, int tid,
                         const float* Apow, float* P) {
    float* br = (float*)sm;
    const int o = tid;
    br[o] = P[(size_t)j * ORD + o];
    __syncthreads();
    const float* M = Apow + (size_t)n * OO;
    float acc = 0.f;
    #pragma unroll 8
    for (int op = 0; op < ORD; ++op) acc += br[op] * M[(size_t)op * ORD + o];
    P[(size_t)(n + j) * ORD + o] = acc;
    __syncthreads();
}

__device__ void ptrib_unit(char* sm, int L, int tid,
                           const float* P, ushort_t* Ptrib) {
    ushort_t (*tile)[72] = (ushort_t (*)[72])sm;
    const int c  = L >> 2;
    const int ob = (L & 3) * 64;
    const int o  = tid & 63;
    const int j4 = tid >> 6;
    for (int jj = j4; jj < CH; jj += 4) {
        float v = (jj <= c) ? P[(size_t)(c - jj) * ORD + ob + o] : 0.f;
        tile[o][jj] = f2bf(v);
    }
    __syncthreads();
    #pragma unroll
    for (int i = 0; i < 2; ++i) {
        int u = tid + i * 256;
        int ol = u >> 3, seg = (u & 7) * 8;
        *(us8*)&Ptrib[((size_t)(c * ORD + ob + ol)) * CH + seg] =
            *(const us8*)&tile[ol][seg];
    }
    __syncthreads();
}

// lend unit: writes MqA[q+1] (and MqA[0] zeros for q==0); q in 0..14
__device__ void lend_unit(char* sm, int i2, int tid,
                          const float* U2, const float* P, float* MqA) {
    float (*As)[68] = (float (*)[68])sm;
    float (*Bs)[68] = (float (*)[68])(sm + 17408);
    const int col0 = (i2 & 3) * 64;
    const int row0 = ((i2 >> 2) & 3) * 64;
    const int q    = i2 >> 4;
    const int tx = tid & 15, ty = tid >> 4;

    for (int i = tid; i < 64 * 16; i += 256) {
        int m = i >> 4, kv = (i & 15) * 4;
        *(float4*)&As[m][kv] =
            *(const float4*)&U2[(size_t)(row0 + m) * T + q * CH + kv];
    }
    for (int i = tid; i < 64 * 16; i += 256) {
        int kk = i >> 4, nv = (i & 15) * 4;
        *(float4*)&Bs[kk][nv] =
            *(const float4*)&P[(size_t)(CH - 1 - kk) * ORD + col0 + nv];
    }
    __syncthreads();
    float acc[4][4] = {};
    for (int kk = 0; kk < 64; ++kk) {
        float a[4], b[4];
        #pragma unroll
        for (int i = 0; i < 4; ++i) a[i] = As[ty * 4 + i][kk];
        #pragma unroll
        for (int j = 0; j < 4; ++j) b[j] = Bs[kk][tx * 4 + j];
        #pragma unroll
        for (int i = 0; i < 4; ++i)
            #pragma unroll
            for (int j = 0; j < 4; ++j) acc[i][j] += a[i] * b[j];
    }
    __syncthreads();
    #pragma unroll
    for (int i = 0; i < 4; ++i) {
        float4 v = make_float4(acc[i][0], acc[i][1], acc[i][2], acc[i][3]);
        size_t off = (size_t)(row0 + ty * 4 + i) * ORD + col0 + tx * 4;
        *(float4*)&MqA[(size_t)(q + 1) * (BD * ORD) + off] = v;
        if (q == 0) {
            float4 z = make_float4(0.f, 0.f, 0.f, 0.f);
            *(float4*)&MqA[off] = z;
        }
    }
}

// squaring tile: Cdst tile = X @ X
__device__ void sq_unit(char* sm, int t, int tid,
                        const float* X, float* Cdst) {
    float (*As)[132] = (float (*)[132])sm;
    float (*Bs)[68]  = (float (*)[68])(sm + 33792);
    const int row0 = (t >> 2) * 64;
    const int col0 = (t & 3) * 64;
    const int tx = tid & 15, ty = tid >> 4;
    float acc[4][4] = {};
    for (int k0 = 0; k0 < ORD; k0 += 128) {
        for (int i = tid; i < 64 * 32; i += 256) {
            int m = i >> 5, kv = (i & 31) * 4;
            *(float4*)&As[m][kv] =
                *(const float4*)&X[(size_t)(row0 + m) * ORD + k0 + kv];
        }
        for (int i = tid; i < 128 * 16; i += 256) {
            int kk = i >> 4, nv = (i & 15) * 4;
            *(float4*)&Bs[kk][nv] =
                *(const float4*)&X[(size_t)(k0 + kk) * ORD + col0 + nv];
        }
        __syncthreads();
        for (int kk = 0; kk < 128; ++kk) {
            float a[4], b[4];
            #pragma unroll
            for (int i = 0; i < 4; ++i) a[i] = As[ty * 4 + i][kk];
            #pragma unroll
            for (int j = 0; j < 4; ++j) b[j] = Bs[kk][tx * 4 + j];
            #pragma unroll
            for (int i = 0; i < 4; ++i)
                #pragma unroll
                for (int j = 0; j < 4; ++j) acc[i][j] += a[i] * b[j];
        }
        __syncthreads();
    }
    #pragma unroll
    for (int i = 0; i < 4; ++i) {
        float4 v = make_float4(acc[i][0], acc[i][1], acc[i][2], acc[i][3]);
        *(float4*)&Cdst[(size_t)(row0 + ty * 4 + i) * ORD + col0 + tx * 4] = v;
    }
}

// scan tile: Mout[q] = Min[q] + Min[q-stride] @ Pw  (dstb -> bf16 out)
__device__ void scan_unit(char* sm, int q, int t, int tid,
                          const float* Min, float* Mout, const float* Pw,
                          int stride, ushort_t* dstb) {
    float (*As)[132] = (float (*)[132])sm;
    float (*Bs)[68]  = (float (*)[68])(sm + 33792);
    const int row0 = ((t >> 2) & 3) * 64;
    const int col0 = (t & 3) * 64;
    const int tx = tid & 15, ty = tid >> 4;
    const float* src = Min + (size_t)q * (BD * ORD);
    float*       dst = Mout ? Mout + (size_t)q * (BD * ORD) : nullptr;
    ushort_t*    db  = dstb ? dstb + (size_t)q * (BD * ORD) : nullptr;

    if (q - stride < 1) {
        for (int i = tid; i < 64 * 64; i += 256) {
            int r = i >> 6, c = i & 63;
            size_t off = (size_t)(row0 + r) * ORD + col0 + c;
            float v = src[off];
            if (db) db[off] = f2bf(v); else dst[off] = v;
        }
        __syncthreads();
        return;
    }

    const float* Ag = Min + (size_t)(q - stride) * (BD * ORD);
    float acc[4][4] = {};
    for (int k0 = 0; k0 < ORD; k0 += 128) {
        for (int i = tid; i < 64 * 32; i += 256) {
            int m = i >> 5, kv = (i & 31) * 4;
            *(float4*)&As[m][kv] =
                *(const float4*)&Ag[(size_t)(row0 + m) * ORD + k0 + kv];
        }
        for (int i = tid; i < 128 * 16; i += 256) {
            int kk = i >> 4, nv = (i & 15) * 4;
            *(float4*)&Bs[kk][nv] =
                *(const float4*)&Pw[(size_t)(k0 + kk) * ORD + col0 + nv];
        }
        __syncthreads();
        for (int kk = 0; kk < 128; ++kk) {
            float a[4], b[4];
            #pragma unroll
            for (int i = 0; i < 4; ++i) a[i] = As[ty * 4 + i][kk];
            #pragma unroll
            for (int j = 0; j < 4; ++j) b[j] = Bs[kk][tx * 4 + j];
            #pragma unroll
            for (int i = 0; i < 4; ++i)
                #pragma unroll
                for (int j = 0; j < 4; ++j) acc[i][j] += a[i] * b[j];
        }
        __syncthreads();
    }
    #pragma unroll
    for (int i = 0; i < 4; ++i) {
        int row = row0 + ty * 4 + i;
        #pragma unroll
        for (int j = 0; j < 4; ++j) {
            int o = col0 + tx * 4 + j;
            size_t off = (size_t)row * ORD + o;
            float val = acc[i][j] + src[off];
            if (db) db[off] = f2bf(val); else dst[off] = val;
        }
    }
    __syncthreads();
}

// ====== k_midp: persistent dataflow kernel (256 blocks, flag-synced) ======
__global__ __launch_bounds__(256) void k_midp(float* __restrict__ Apow,
                                              ushort_t* __restrict__ Apb,
                                              float* __restrict__ P,
                                              ushort_t* __restrict__ Ptrib,
                                              const float* __restrict__ U2,
                                              float* __restrict__ MqA,
                                              float* __restrict__ Lend,
                                              ushort_t* __restrict__ Mqb,
                                              float* __restrict__ A128,
                                              float* __restrict__ A256,
                                              float* __restrict__ A512,
                                              uint32_t* __restrict__ F) {
    __shared__ __align__(16) char sm[77824];
    const int tid = threadIdx.x;
    float* A64 = Apow + (size_t)CH * OO;

    for (int uid = blockIdx.x; uid < 2655; uid += 256) {
        if (uid < 1071) {                          // pow phases
            int n, base;
            if      (uid < 17)  { n = 1;  base = 0;   }
            else if (uid < 51)  { n = 2;  base = 17;  }
            else if (uid < 119) { n = 4;  base = 51;  }
            else if (uid < 255) { n = 8;  base = 119; }
            else if (uid < 527) { n = 16; base = 255; }
            else                { n = 32; base = 527; }
            int L = uid - base;
            if (L < 16 * n) {
                int z = L >> 4, t = L & 15;
                gwait(F + (z + 1), 16);
                gwait(F + n, 16);
                pow_unit(sm, z, (t >> 2) & 3, t & 3, tid, Apow, Apb, n);
                gpost(F + (n + z + 1), 1);
            } else {
                int j = L - 16 * n;
                gwait(F + 65, (uint32_t)n);
                gwait(F + n, 16);
                p_double(sm, j, n, tid, Apow, P);
                gpost(F + 65, 1);
            }
        } else if (uid < 1583) {                   // prep1
            int L = uid - 1071;
            gwait(F + 65, 64);
            if (L < 256) {
                ptrib_unit(sm, L, tid, P, Ptrib);
            } else {
                int i2 = L - 256;
                int q = i2 >> 4;
                if (q < 15) {
                    lend_unit(sm, i2, tid, U2, P, MqA);
                    gpost(F + 70 + (q + 1), 1);
                    if (q == 0) gpost(F + 70 + 0, 1);
                    gpost(F + 66, 1);
                }
            }
        } else if (uid < 1599) {                   // sq128 = A64^2
            gwait(F + 64, 16);
            sq_unit(sm, uid - 1583, tid, A64, A128);
            gpost(F + 67, 1);
        } else if (uid < 1855) {                   // scan1: MqA->Lend, A64
            int L = uid - 1599; int q = L >> 4; int t = L & 15;
            gwait(F + 70 + q, 16);
            if (q - 1 >= 1) { gwait(F + 70 + (q - 1), 16); gwait(F + 64, 16); }
            scan_unit(sm, q, t, tid, MqA, Lend, A64, 1, nullptr);
            gpost(F + 86 + q, 1);
        } else if (uid < 1871) {                   // sq256 = A128^2 (into U2)
            gwait(F + 67, 16);
            gwait(F + 66, 240);                    // WAR vs lend's U2 reads
            sq_unit(sm, uid - 1855, tid, A128, A256);
            gpost(F + 68, 1);
        } else if (uid < 2127) {                   // scan2: Lend->MqA, A128
            int L = uid - 1871; int q = L >> 4; int t = L & 15;
            gwait(F + 86 + q, 16);
            if (q + 1 <= 15) gwait(F + 86 + (q + 1), 16);   // WAR on MqA[q]
            if (q - 2 >= 1) { gwait(F + 86 + (q - 2), 16); gwait(F + 67, 16); }
            scan_unit(sm, q, t, tid, Lend, MqA, A128, 2, nullptr);
            gpost(F + 102 + q, 1);
        } else if (uid < 2143) {                   // sq512 = A256^2 (into U2)
            gwait(F + 68, 16);
            gwait(F + 66, 240);
            sq_unit(sm, uid - 2127, tid, A256, A512);
            gpost(F + 69, 1);
        } else if (uid < 2399) {                   // scan4: MqA->Lend, A256
            int L = uid - 2143; int q = L >> 4; int t = L & 15;
            gwait(F + 102 + q, 16);
            if (q + 2 <= 15) gwait(F + 102 + (q + 2), 16);  // WAR on Lend[q]
            if (q - 4 >= 1) { gwait(F + 102 + (q - 4), 16); gwait(F + 68, 16); }
            scan_unit(sm, q, t, tid, MqA, Lend, A256, 4, nullptr);
            gpost(F + 118 + q, 1);
        } else {                                   // scan8: Lend->Mqb, A512
            int L = uid - 2399; int q = L >> 4; int t = L & 15;
            gwait(F + 118 + q, 16);
            if (q - 8 >= 1) { gwait(F + 118 + (q - 8), 16); gwait(F + 69, 16); }
            scan_unit(sm, q, t, tid, Lend, nullptr, A512, 8, Mqb);
        }
    }
}

// ====== MFMA GEMM 1 (m97, BK=64, T2 swizzle): mbuf = [U2|Mq] @ [Ptrib;Apb] ==
__global__ __launch_bounds__(256) void k_gemm24(const ushort_t* __restrict__ U2b,
                                                const ushort_t* __restrict__ Mqb,
                                                const ushort_t* __restrict__ Ptrib,
                                                const ushort_t* __restrict__ Apb,
                                                ushort_t* __restrict__ mbuf,
                                                int gbase, int nrows) {
    __shared__ __align__(16) char sm[128 * 136 * 2];   // st aliases As+Bs
    ushort_t* As = (ushort_t*)sm;                      // 128*64
    ushort_t* Bs = As + 128 * 64;
    ushort_t (*st)[136] = (ushort_t (*)[136])sm;
    const int q       = blockIdx.z;
    const int rowbase = blockIdx.y * 128;
    const int colbase = blockIdx.x * 128;
    const int tid  = threadIdx.x;
    const int lane = tid & 63;
    const int wid  = tid >> 6;
    const int wr = wid >> 1, wc = wid & 1;
    const int lr = lane & 15, hi = lane >> 4;

    f32x4 acc[4][4];
    #pragma unroll
    for (int m = 0; m < 4; ++m)
        #pragma unroll
        for (int n = 0; n < 4; ++n) acc[m][n] = 0.f;

    for (int s = 0; s < KTOT24 / 64; ++s) {           // 5 steps of BK=64
        const int k0 = s * 64;
        #pragma unroll
        for (int i = 0; i < 4; ++i) {
            const int ub = (wid * 4 + i) * 64;
            const int u  = ub + lane;
            const int row = u >> 3;
            const int sw  = (((u & 7) ^ (row & 7))) * 8;
            int gr = rowbase + row;
            if (gr >= nrows) gr = nrows - 1;
            const ushort_t *ga, *gb;
            if (s == 0) {
                ga = &U2b[(size_t)(gbase + gr) * T + q * CH + sw];
                gb = &Ptrib[(size_t)(colbase + row) * CH + sw];
            } else {
                ga = &Mqb[((size_t)q * BD + gbase + gr) * ORD + (k0 - CH) + sw];
                gb = &Apb[(size_t)(colbase + row) * ORD + (k0 - CH) + sw];
            }
            gl_lds16(ga, &As[ub * 8]);
            gl_lds16(gb, &Bs[ub * 8]);
        }
        __syncthreads();
        #pragma unroll
        for (int t = 0; t < 2; ++t) {
            bf16x8 af[4], bfv[4];
            #pragma unroll
            for (int m = 0; m < 4; ++m) {
                int r = wr * 64 + m * 16 + lr;
                int un = (t * 4 + hi) ^ (r & 7);
                af[m] = *(const bf16x8*)&As[r * 64 + un * 8];
            }
            #pragma unroll
            for (int n = 0; n < 4; ++n) {
                int r = wc * 64 + n * 16 + lr;
                int un = (t * 4 + hi) ^ (r & 7);
                bfv[n] = *(const bf16x8*)&Bs[r * 64 + un * 8];
            }
            #pragma unroll
            for (int m = 0; m < 4; ++m)
                #pragma unroll
                for (int n = 0; n < 4; ++n)
                    acc[m][n] = __builtin_amdgcn_mfma_f32_16x16x32_bf16(af[m], bfv[n], acc[m][n], 0, 0, 0);
        }
        __syncthreads();
    }

    #pragma unroll
    for (int m = 0; m < 4; ++m)
        #pragma unroll
        for (int n = 0; n < 4; ++n)
            #pragma unroll
            for (int r = 0; r < 4; ++r)
                st[wr * 64 + m * 16 + hi * 4 + r]
                  [wc * 64 + n * 16 + lr] = f2bf(acc[m][n][r]);
    __syncthreads();

    const int c     = colbase >> 8;
    const int obase = colbase & 255;
    #pragma unroll
    for (int i = 0; i < 8; ++i) {
        int u  = tid + i * 256;
        int rl = u >> 4, cb = (u & 15) * 8;
        int grow = rowbase + rl;
        if (grow < nrows) {
            int bl = grow >> 3, d = grow & 7;
            size_t addr = ((size_t)(bl * T + q * CH + c)) * DO + (d << 8) + obase + cb;
            *(us8*)&mbuf[addr] = *(const us8*)&st[rl][cb];
        }
    }
}

// ====== MFMA GEMM 2: 256x256 tile, 8 waves, 64 ks-steps of K=32,
// 4 LDS slots/operand, 3-step prefetch, counted vmcnt(8) (T2+T3+T4+T5).
__global__ __launch_bounds__(512) void k_gemm5(const ushort_t* __restrict__ mbuf,
                                               const ushort_t* __restrict__ Whbt,
                                               const float* __restrict__ bh,
                                               float* __restrict__ out, int np) {
    __shared__ ushort_t A4[4][256 * 32];
    __shared__ ushort_t B4[4][256 * 32];
    const int nwg = np * 2;
    int wg = blockIdx.x;
    int bx, by;
    if ((nwg & 7) == 0 && (np & 3) == 0) {
        int xcd = wg & 7, j = wg >> 3;
        bx = j & 1;
        by = xcd * (np >> 3) + (j >> 1);
    } else { bx = wg & 1; by = wg >> 1; }
    const int rowbase = by * 256;
    const int colbase = bx * 256;
    const int tid  = threadIdx.x;
    const int lane = tid & 63;
    const int wid  = tid >> 6;
    const int wr = wid >> 2, wcw = wid & 3;
    const int lr = lane & 15, hi = lane >> 4;

    f32x4 acc[8][4];
    #pragma unroll
    for (int m = 0; m < 8; ++m)
        #pragma unroll
        for (int n = 0; n < 4; ++n) acc[m][n] = 0.f;

    const int NT = DO / 32;

    auto STAGE_A = [&](int s) {
        const int k0 = s * 32;
        ushort_t* slot = A4[s & 3];
        #pragma unroll
        for (int i = 0; i < 2; ++i) {
            const int ug = i * 512 + wid * 64;
            const int u  = ug + lane;
            const int row = u >> 2, uu = u & 3;
            const int col = k0 + ((uu ^ ((row >> 1) & 3)) * 8);
            gl_lds16(&mbuf[(size_t)(rowbase + row) * DO + col], &slot[ug * 8]);
        }
    };
    auto STAGE_B = [&](int s) {
        const int k0 = s * 32;
        ushort_t* slot = B4[s & 3];
        #pragma unroll
        for (int i = 0; i < 2; ++i) {
            const int ug = i * 512 + wid * 64;
            const int u  = ug + lane;
            const int row = u >> 2, uu = u & 3;
            const int col = k0 + ((uu ^ ((row >> 1) & 3)) * 8);
            gl_lds16(&Whbt[(size_t)(colbase + row) * DO + col], &slot[ug * 8]);
        }
    };

    STAGE_A(0); STAGE_B(0);
    STAGE_A(1); STAGE_B(1);
    STAGE_A(2); STAGE_B(2);
    asm volatile("s_waitcnt vmcnt(8)" ::: "memory");
    __builtin_amdgcn_s_barrier();

    for (int k = 0; k < NT; ++k) {
        const int sl = k & 3;
        ushort_t* As_ = A4[sl];
        ushort_t* Bs_ = B4[sl];
        bf16x8 bv[4], av[4];

        #pragma unroll
        for (int n = 0; n < 4; ++n) {
            int r = wcw * 64 + n * 16 + lr;
            bv[n] = *(const bf16x8*)&Bs_[r * 32 + ((hi ^ ((r >> 1) & 3)) * 8)];
        }
        #pragma unroll
        for (int m = 0; m < 4; ++m) {
            int r = wr * 128 + m * 16 + lr;
            av[m] = *(const bf16x8*)&As_[r * 32 + ((hi ^ ((r >> 1) & 3)) * 8)];
        }
        if (k + 3 < NT) STAGE_A(k + 3);
        __builtin_amdgcn_s_barrier();
        __builtin_amdgcn_s_setprio(1);
        #pragma unroll
        for (int m = 0; m < 4; ++m)
            #pragma unroll
            for (int n = 0; n < 4; ++n)
                acc[m][n] = __builtin_amdgcn_mfma_f32_16x16x32_bf16(av[m], bv[n], acc[m][n], 0, 0, 0);
        __builtin_amdgcn_s_setprio(0);

        #pragma unroll
        for (int m = 0; m < 4; ++m) {
            int r = wr * 128 + 64 + m * 16 + lr;
            av[m] = *(const bf16x8*)&As_[r * 32 + ((hi ^ ((r >> 1) & 3)) * 8)];
        }
        if (k + 3 < NT) STAGE_B(k + 3);
        __builtin_amdgcn_s_setprio(1);
        #pragma unroll
        for (int m = 0; m < 4; ++m)
            #pragma unroll
            for (int n = 0; n < 4; ++n)
                acc[4 + m][n] = __builtin_amdgcn_mfma_f32_16x16x32_bf16(av[m], bv[n], acc[4 + m][n], 0, 0, 0);
        __builtin_amdgcn_s_setprio(0);

        if (k < NT - 1) {
            if (k < NT - 3)       asm volatile("s_waitcnt vmcnt(8)" ::: "memory");
            else if (k == NT - 3) asm volatile("s_waitcnt vmcnt(4)" ::: "memory");
            else                  asm volatile("s_waitcnt vmcnt(0)" ::: "memory");
            __builtin_amdgcn_s_barrier();
        }
    }

    #pragma unroll
    for (int m = 0; m < 8; ++m) {
        #pragma unroll
        for (int n = 0; n < 4; ++n) {
            int col = colbase + wcw * 64 + n * 16 + lr;
            float bias = bh[col];
            #pragma unroll
            for (int r = 0; r < 4; ++r) {
                int grow = rowbase + wr * 128 + m * 16 + hi * 4 + r;
                out[(size_t)grow * HID + col] = tanhf(acc[m][n][r] + bias);
            }
        }
    }
}

// ---------------- launch ----------------
extern "C" void kernel_launch(void* const* d_in, const int* in_sizes, int n_in,
                              void* d_out, int out_size, void* d_ws, size_t ws_size,
                              hipStream_t stream) {
    const float* x    = (const float*)d_in[0];
    const float* kern = (const float*)d_in[1];
    const float* Wh   = (const float*)d_in[2];
    const float* bh   = (const float*)d_in[3];
    const float* A    = (const float*)d_in[4];
    const float* Brow = (const float*)d_in[5];
    float* out = (float*)d_out;

    char* base = (char*)d_ws;
    float*    U2    = (float*)(base + OFF_U2);
    float*    P     = (float*)(base + OFF_P);
    float*    Apow  = (float*)(base + OFF_APOW);
    float*    MqA   = (float*)(base + OFF_MQ);
    float*    Lend  = (float*)(base + OFF_LEND);
    ushort_t* U2b   = (ushort_t*)(base + OFF_U2B);
    ushort_t* Ptrib = (ushort_t*)(base + OFF_PTRB);
    ushort_t* Apb   = (ushort_t*)(base + OFF_APB);
    ushort_t* Whbt  = (ushort_t*)(base + OFF_WHBT);
    ushort_t* Mqb   = (ushort_t*)(base + OFF_MQB);
    uint32_t* F     = (uint32_t*)(base + OFF_FLG);
    ushort_t* mbuf  = (ushort_t*)(base + OFF_MBUF);

    float* A128 = Apow;                    // Apow slot 0 (unused)
    float* A256 = U2;                      // U2 f32 dead after lend units
    float* A512 = U2 + OO;

    // choose largest batch group whose bf16 mbuf fits
    int G = 1;
    for (int g = 32; g >= 1; g >>= 1) {
        if (OFF_MBUF + (size_t)g * T * DO * 2 <= ws_size) { G = g; break; }
    }
    const int ngroups = BSZ / G;

    // prep0: U proj + A copy/transpose + Wh transpose + P[0] + flag init
    k_prep0<<<dim3(2113), 256, 0, stream>>>(
        x, kern, U2, U2b, A, Apow, Apb, Wh, Whbt, Brow, P, F);

    // persistent dataflow mid-section (pow chain + P + prep1 + scan)
    k_midp<<<dim3(256), 256, 0, stream>>>(
        Apow, Apb, P, Ptrib, U2, MqA, Lend, Mqb, A128, A256, A512, F);

    // per batch-group: MFMA m-materialization + MFMA output GEMM
    for (int g = 0; g < ngroups; ++g) {
        const int gbase = g * G * MD;
        const int nrows = G * MD;
        const int gy24  = (nrows + 127) / 128;
        k_gemm24<<<dim3((CH * ORD) / 128, gy24, NQ), 256, 0, stream>>>(
            U2b, Mqb, Ptrib, Apb, mbuf, gbase, nrows);
        const int np = (G * T) / 256;
        k_gemm5<<<dim3(np * 2), 512, 0, stream>>>(
            mbuf, Whbt, bh, out + (size_t)g * G * T * HID, np);
    }
}

// Round 18
// 340.821 us; speedup vs baseline: 2.3195x; 2.3195x over previous
//
#include <hip/hip_runtime.h>
#include <cstdint>
#include <cstddef>

// ---------------- problem constants ----------------
constexpr int BSZ = 32;
constexpr int T   = 1024;
constexpr int ID  = 256;
constexpr int MD  = 8;
constexpr int ORD = 256;
constexpr int HID = 512;
constexpr int BD  = BSZ * MD;   // 256
constexpr int CH  = 64;
constexpr int NQ  = T / CH;     // 16
constexpr int DO  = MD * ORD;   // 2048
constexpr int OO  = ORD * ORD;  // 65536
constexpr int KTOT24 = CH + ORD; // 320

typedef unsigned short ushort_t;
typedef __attribute__((ext_vector_type(8))) short bf16x8;
typedef __attribute__((ext_vector_type(8))) unsigned short us8;
typedef __attribute__((ext_vector_type(4))) float f32x4;

__device__ inline ushort_t f2bf(float f) {
    union { float f; uint32_t u; } v; v.f = f;
    uint32_t r = v.u + 0x7fffu + ((v.u >> 16) & 1u);
    return (ushort_t)(r >> 16);
}

// async global->LDS, 16B per lane; LDS dest = wave-uniform base + lane*16
__device__ inline void gl_lds16(const void* g, void* l) {
    __builtin_amdgcn_global_load_lds(
        (const __attribute__((address_space(1))) void*)g,
        (__attribute__((address_space(3))) void*)l, 16, 0, 0);
}

// ---------------- workspace layout (bytes) ----------------
constexpr size_t AL = 256;
constexpr size_t alup(size_t x) { return (x + AL - 1) & ~(AL - 1); }
constexpr size_t OFF_U2   = 0;                                          // f32 BD*T (dead after prep1; reused A256/A512)
constexpr size_t OFF_P    = alup(OFF_U2   + (size_t)BD * T * 4);        // f32 CH*ORD
constexpr size_t OFF_APOW = alup(OFF_P    + (size_t)CH * ORD * 4);      // f32 (CH+1)*OO (slot 0 = A128)
constexpr size_t OFF_MQ   = alup(OFF_APOW + (size_t)(CH + 1) * OO * 4); // f32 NQ*BD*ORD (scan A)
constexpr size_t OFF_LEND = alup(OFF_MQ   + (size_t)NQ * BD * ORD * 4); // f32 NQ*BD*ORD (scan B)
constexpr size_t OFF_U2B  = alup(OFF_LEND + (size_t)NQ * BD * ORD * 4); // bf16 BD*T
constexpr size_t OFF_PTRB = alup(OFF_U2B  + (size_t)BD * T * 2);        // bf16 (CH*ORD)*CH
constexpr size_t OFF_APB  = alup(OFF_PTRB + (size_t)CH * ORD * CH * 2); // bf16 CH*ORD*ORD
constexpr size_t OFF_WHBT = alup(OFF_APB  + (size_t)CH * ORD * ORD * 2);// bf16 HID*DO
constexpr size_t OFF_MQB  = alup(OFF_WHBT + (size_t)HID * DO * 2);      // bf16 NQ*BD*ORD
constexpr size_t OFF_MBUF = alup(OFF_MQB  + (size_t)NQ * BD * ORD * 2); // bf16 G*T*DO

// ====== fused prep0: k_u (0..1023) + copyAT (1024..1087) + whbt + P0 ======
__global__ __launch_bounds__(256) void k_prep0(const float* __restrict__ x,
                                               const float* __restrict__ kern,
                                               float* __restrict__ U2,
                                               ushort_t* __restrict__ U2b,
                                               const float* __restrict__ A,
                                               float* __restrict__ Apow,
                                               ushort_t* __restrict__ Apb,
                                               const float* __restrict__ Wh,
                                               ushort_t* __restrict__ Whbt,
                                               const float* __restrict__ Brow,
                                               float* __restrict__ P) {
    __shared__ __align__(16) char sm[32 * (ID + 1) * 4 + ID * MD * 4];
    const int bid = blockIdx.x;
    const int tid = threadIdx.x;

    if (bid < 1024) {                      // ---- U2 projection ----
        float (*xs)[ID + 1] = (float (*)[ID + 1])sm;
        float (*ks)[MD]     = (float (*)[MD])(sm + 32 * (ID + 1) * 4);
        const int b  = bid / (T / 32);
        const int t0 = (bid % (T / 32)) * 32;
        for (int i = tid; i < ID * MD; i += 256) ks[i / MD][i % MD] = kern[i];
        const float* xp = x + ((size_t)b * T + t0) * ID;
        for (int i = tid; i < (32 * ID) / 4; i += 256) {
            float4 v = ((const float4*)xp)[i];
            int r = i >> 6, c = (i & 63) * 4;
            xs[r][c] = v.x; xs[r][c + 1] = v.y; xs[r][c + 2] = v.z; xs[r][c + 3] = v.w;
        }
        __syncthreads();
        const int d  = tid / 32;
        const int tl = tid % 32;
        float acc = 0.f;
        #pragma unroll 8
        for (int i = 0; i < ID; ++i) acc += xs[tl][i] * ks[i][d];
        size_t idx = ((size_t)b * MD + d) * T + t0 + tl;
        U2[idx]  = acc;
        U2b[idx] = f2bf(acc);
    } else if (bid < 1088) {               // ---- A -> Apow[1] + Apb[0]^T ----
        float (*t)[33] = (float (*)[33])sm;
        const int i2 = bid - 1024;
        const int o0 = (i2 & 7) * 32, p0 = (i2 >> 3) * 32;
        const int tx = tid & 31, ty = tid >> 5;
        #pragma unroll
        for (int p = 0; p < 4; ++p) {
            int r = ty + p * 8;
            float v = A[(size_t)(p0 + r) * ORD + o0 + tx];
            Apow[OO + (size_t)(p0 + r) * ORD + o0 + tx] = v;
            t[r][tx] = v;
        }
        __syncthreads();
        #pragma unroll
        for (int p = 0; p < 4; ++p) {
            int r = ty + p * 8;
            Apb[(size_t)(o0 + r) * ORD + p0 + tx] = f2bf(t[tx][r]);
        }
    } else if (bid < 2112) {               // ---- Whbt transpose ----
        float (*t)[33] = (float (*)[33])sm;
        const int i2 = bid - 1088;
        const int k0 = (i2 & 63) * 32, h0 = (i2 >> 6) * 32;
        const int tx = tid & 31, ty = tid >> 5;
        #pragma unroll
        for (int p = 0; p < 4; ++p) {
            int r = ty + p * 8;
            t[r][tx] = Wh[(size_t)(k0 + r) * HID + h0 + tx];
        }
        __syncthreads();
        #pragma unroll
        for (int p = 0; p < 4; ++p) {
            int r = ty + p * 8;
            Whbt[(size_t)(h0 + r) * DO + k0 + tx] = f2bf(t[tx][r]);
        }
    } else {                               // ---- P[0] = Brow ----
        P[tid] = Brow[tid];
    }
}

// ============== mid-section device bodies (K=128 staged, float4) ==========
// pow sm layout: As f32[64][132] @0 (33792B), Bs f32[128][68] @33792 (34816B),
//                tr ushort[64][72] @68608 (9216B) => 77824B total
// scan sm layout: As + Bs only => 68608B

// pow: Apow[n+z+1] = Apow[z+1] @ Apow[n]; also Apb[e-1] = bf16(A^e)^T
__device__ void pow_body(char* sm, int bid, int tid,
                         float* Apow, ushort_t* Apb, int n) {
    float (*As)[132] = (float (*)[132])sm;
    float (*Bs)[68]  = (float (*)[68])(sm + 33792);
    ushort_t (*tr)[72] = (ushort_t (*)[72])(sm + 68608);
    const int z    = bid >> 4;
    const int row0 = ((bid >> 2) & 3) * 64;
    const int col0 = (bid & 3) * 64;
    const int tx = tid & 15, ty = tid >> 4;
    const float* Ag = Apow + (size_t)(z + 1) * OO;
    const float* Bg = Apow + (size_t)n * OO;
    float*       Cg = Apow + (size_t)(n + z + 1) * OO;

    float acc[4][4] = {};
    for (int k0 = 0; k0 < ORD; k0 += 128) {
        for (int i = tid; i < 64 * 32; i += 256) {
            int m = i >> 5, kv = (i & 31) * 4;
            *(float4*)&As[m][kv] =
                *(const float4*)&Ag[(size_t)(row0 + m) * ORD + k0 + kv];
        }
        for (int i = tid; i < 128 * 16; i += 256) {
            int kk = i >> 4, nv = (i & 15) * 4;
            *(float4*)&Bs[kk][nv] =
                *(const float4*)&Bg[(size_t)(k0 + kk) * ORD + col0 + nv];
        }
        __syncthreads();
        for (int kk = 0; kk < 128; ++kk) {
            float a[4], b[4];
            #pragma unroll
            for (int i = 0; i < 4; ++i) a[i] = As[ty * 4 + i][kk];
            #pragma unroll
            for (int j = 0; j < 4; ++j) b[j] = Bs[kk][tx * 4 + j];
            #pragma unroll
            for (int i = 0; i < 4; ++i)
                #pragma unroll
                for (int j = 0; j < 4; ++j) acc[i][j] += a[i] * b[j];
        }
        __syncthreads();
    }
    ushort_t* ap = Apb + (size_t)(n + z) * OO;
    #pragma unroll
    for (int i = 0; i < 4; ++i) {
        float4 v = make_float4(acc[i][0], acc[i][1], acc[i][2], acc[i][3]);
        *(float4*)&Cg[(size_t)(row0 + ty * 4 + i) * ORD + col0 + tx * 4] = v;
        #pragma unroll
        for (int j = 0; j < 4; ++j)
            tr[tx * 4 + j][ty * 4 + i] = f2bf(acc[i][j]);
    }
    __syncthreads();
    #pragma unroll
    for (int i = 0; i < 2; ++i) {
        int u = tid + i * 256;
        int cc = u >> 3, seg = (u & 7) * 8;
        *(us8*)&ap[(size_t)(col0 + cc) * ORD + row0 + seg] =
            *(const us8*)&tr[cc][seg];
    }
}

// ====== pow launch: 16n pow blocks + n P-doubling blocks ======
// P[n+j] = P[j] @ A^n
__global__ __launch_bounds__(256) void k_pow_w(float* __restrict__ Apow,
                                               ushort_t* __restrict__ Apb,
                                               float* __restrict__ P, int n) {
    __shared__ __align__(16) char sm[77824];
    const int bid = blockIdx.x;
    const int tid = threadIdx.x;
    if (bid < 16 * n) { pow_body(sm, bid, tid, Apow, Apb, n); return; }
    float* br = (float*)sm;
    const int j = bid - 16 * n;
    const int o = tid;
    br[o] = P[(size_t)j * ORD + o];
    __syncthreads();
    const float* M = Apow + (size_t)n * OO;
    float acc = 0.f;
    #pragma unroll 8
    for (int op = 0; op < ORD; ++op) acc += br[op] * M[(size_t)op * ORD + o];
    P[(size_t)(n + j) * ORD + o] = acc;
}

// ptrib (bid<256) + lend/scan-init (256<=bid<512)
__device__ void prep1_body(char* sm, int bid, int tid,
                           const float* P, ushort_t* Ptrib,
                           const float* U2, float* Lend, float* MqA) {
    if (bid < 256) {
        ushort_t (*tile)[72] = (ushort_t (*)[72])sm;
        const int c  = bid >> 2;
        const int ob = (bid & 3) * 64;
        const int o  = tid & 63;
        const int j4 = tid >> 6;
        for (int jj = j4; jj < CH; jj += 4) {
            float v = (jj <= c) ? P[(size_t)(c - jj) * ORD + ob + o] : 0.f;
            tile[o][jj] = f2bf(v);
        }
        __syncthreads();
        #pragma unroll
        for (int i = 0; i < 2; ++i) {
            int u = tid + i * 256;
            int ol = u >> 3, seg = (u & 7) * 8;
            *(us8*)&Ptrib[((size_t)(c * ORD + ob + ol)) * CH + seg] =
                *(const us8*)&tile[ol][seg];
        }
    } else {
        float (*As)[68] = (float (*)[68])sm;
        float (*Bs)[68] = (float (*)[68])(sm + 17408);
        const int i2   = bid - 256;
        const int col0 = (i2 & 3) * 64;
        const int row0 = ((i2 >> 2) & 3) * 64;
        const int q    = i2 >> 4;
        const int tx = tid & 15, ty = tid >> 4;

        // single K=64 step (CH=64)
        for (int i = tid; i < 64 * 16; i += 256) {
            int m = i >> 4, kv = (i & 15) * 4;
            *(float4*)&As[m][kv] =
                *(const float4*)&U2[(size_t)(row0 + m) * T + q * CH + kv];
        }
        for (int i = tid; i < 64 * 16; i += 256) {
            int kk = i >> 4, nv = (i & 15) * 4;
            *(float4*)&Bs[kk][nv] =
                *(const float4*)&P[(size_t)(CH - 1 - kk) * ORD + col0 + nv];
        }
        __syncthreads();
        float acc[4][4] = {};
        for (int kk = 0; kk < 64; ++kk) {
            float a[4], b[4];
            #pragma unroll
            for (int i = 0; i < 4; ++i) a[i] = As[ty * 4 + i][kk];
            #pragma unroll
            for (int j = 0; j < 4; ++j) b[j] = Bs[kk][tx * 4 + j];
            #pragma unroll
            for (int i = 0; i < 4; ++i)
                #pragma unroll
                for (int j = 0; j < 4; ++j) acc[i][j] += a[i] * b[j];
        }
        __syncthreads();
        #pragma unroll
        for (int i = 0; i < 4; ++i) {
            float4 v = make_float4(acc[i][0], acc[i][1], acc[i][2], acc[i][3]);
            size_t off = (size_t)(row0 + ty * 4 + i) * ORD + col0 + tx * 4;
            *(float4*)&Lend[(size_t)q * (BD * ORD) + off] = v;
            if (q + 1 < NQ) *(float4*)&MqA[(size_t)(q + 1) * (BD * ORD) + off] = v;
            if (q == 0) {
                float4 z = make_float4(0.f, 0.f, 0.f, 0.f);
                *(float4*)&MqA[off] = z;
            }
        }
    }
}

__global__ __launch_bounds__(256) void k_prep1_w(const float* __restrict__ P,
                                                 ushort_t* __restrict__ Ptrib,
                                                 const float* __restrict__ U2,
                                                 float* __restrict__ Lend,
                                                 float* __restrict__ MqA) {
    __shared__ __align__(16) char sm[34816];
    prep1_body(sm, blockIdx.x, threadIdx.x, P, Ptrib, U2, Lend, MqA);
}

// scan (bid<256) + optional squaring (256<=bid<272 when Pnext); K=128 steps
__device__ void scan_body(char* sm, int bid, int tid,
                          const float* Min, float* Mout, const float* Pw,
                          int stride, ushort_t* dstb, float* Pnext) {
    float (*As)[132] = (float (*)[132])sm;
    float (*Bs)[68]  = (float (*)[68])(sm + 33792);
    const int tx = tid & 15, ty = tid >> 4;

    if (bid >= 256) {                     // squaring tile-group
        if (!Pnext || bid >= 272) return;
        const int i3 = bid - 256;
        const int row0 = (i3 >> 2) * 64;
        const int col0 = (i3 & 3) * 64;
        float acc[4][4] = {};
        for (int k0 = 0; k0 < ORD; k0 += 128) {
            for (int i = tid; i < 64 * 32; i += 256) {
                int m = i >> 5, kv = (i & 31) * 4;
                *(float4*)&As[m][kv] =
                    *(const float4*)&Pw[(size_t)(row0 + m) * ORD + k0 + kv];
            }
            for (int i = tid; i < 128 * 16; i += 256) {
                int kk = i >> 4, nv = (i & 15) * 4;
                *(float4*)&Bs[kk][nv] =
                    *(const float4*)&Pw[(size_t)(k0 + kk) * ORD + col0 + nv];
            }
            __syncthreads();
            for (int kk = 0; kk < 128; ++kk) {
                float a[4], b[4];
                #pragma unroll
                for (int i = 0; i < 4; ++i) a[i] = As[ty * 4 + i][kk];
                #pragma unroll
                for (int j = 0; j < 4; ++j) b[j] = Bs[kk][tx * 4 + j];
                #pragma unroll
                for (int i = 0; i < 4; ++i)
                    #pragma unroll
                    for (int j = 0; j < 4; ++j) acc[i][j] += a[i] * b[j];
            }
            __syncthreads();
        }
        #pragma unroll
        for (int i = 0; i < 4; ++i) {
            float4 v = make_float4(acc[i][0], acc[i][1], acc[i][2], acc[i][3]);
            *(float4*)&Pnext[(size_t)(row0 + ty * 4 + i) * ORD + col0 + tx * 4] = v;
        }
        return;
    }

    const int q    = bid >> 4;
    const int row0 = ((bid >> 2) & 3) * 64;
    const int col0 = (bid & 3) * 64;
    const float* src = Min + (size_t)q * (BD * ORD);
    float*       dst = Mout + (size_t)q * (BD * ORD);
    ushort_t*    db  = dstb ? dstb + (size_t)q * (BD * ORD) : nullptr;

    if (q - stride < 1) {                 // copy through (M_0 = 0 source)
        for (int i = tid; i < 64 * 64; i += 256) {
            int r = i >> 6, c = i & 63;
            size_t off = (size_t)(row0 + r) * ORD + col0 + c;
            float v = src[off];
            if (db) db[off] = f2bf(v); else dst[off] = v;
        }
        return;
    }

    const float* Ag = Min + (size_t)(q - stride) * (BD * ORD);
    float acc[4][4] = {};
    for (int k0 = 0; k0 < ORD; k0 += 128) {
        for (int i = tid; i < 64 * 32; i += 256) {
            int m = i >> 5, kv = (i & 31) * 4;
            *(float4*)&As[m][kv] =
                *(const float4*)&Ag[(size_t)(row0 + m) * ORD + k0 + kv];
        }
        for (int i = tid; i < 128 * 16; i += 256) {
            int kk = i >> 4, nv = (i & 15) * 4;
            *(float4*)&Bs[kk][nv] =
                *(const float4*)&Pw[(size_t)(k0 + kk) * ORD + col0 + nv];
        }
        __syncthreads();
        for (int kk = 0; kk < 128; ++kk) {
            float a[4], b[4];
            #pragma unroll
            for (int i = 0; i < 4; ++i) a[i] = As[ty * 4 + i][kk];
            #pragma unroll
            for (int j = 0; j < 4; ++j) b[j] = Bs[kk][tx * 4 + j];
            #pragma unroll
            for (int i = 0; i < 4; ++i)
                #pragma unroll
                for (int j = 0; j < 4; ++j) acc[i][j] += a[i] * b[j];
        }
        __syncthreads();
    }
    #pragma unroll
    for (int i = 0; i < 4; ++i) {
        int row = row0 + ty * 4 + i;
        #pragma unroll
        for (int j = 0; j < 4; ++j) {
            int o = col0 + tx * 4 + j;
            size_t off = (size_t)row * ORD + o;
            float val = acc[i][j] + src[off];
            if (db) db[off] = f2bf(val); else dst[off] = val;
        }
    }
}

__global__ __launch_bounds__(256) void k_scan_w(const float* __restrict__ Min,
                                                float* __restrict__ Mout,
                                                const float* __restrict__ Pw,
                                                int stride,
                                                ushort_t* __restrict__ dstb,
                                                float* __restrict__ Pnext) {
    __shared__ __align__(16) char sm[68608];
    scan_body(sm, blockIdx.x, threadIdx.x, Min, Mout, Pw, stride, dstb, Pnext);
}

// ====== MFMA GEMM 1 (m97, BK=64, T2 swizzle): mbuf = [U2|Mq] @ [Ptrib;Apb] ==
__global__ __launch_bounds__(256) void k_gemm24(const ushort_t* __restrict__ U2b,
                                                const ushort_t* __restrict__ Mqb,
                                                const ushort_t* __restrict__ Ptrib,
                                                const ushort_t* __restrict__ Apb,
                                                ushort_t* __restrict__ mbuf,
                                                int gbase, int nrows) {
    __shared__ __align__(16) char sm[128 * 136 * 2];   // st aliases As+Bs
    ushort_t* As = (ushort_t*)sm;                      // 128*64
    ushort_t* Bs = As + 128 * 64;
    ushort_t (*st)[136] = (ushort_t (*)[136])sm;
    const int q       = blockIdx.z;
    const int rowbase = blockIdx.y * 128;
    const int colbase = blockIdx.x * 128;
    const int tid  = threadIdx.x;
    const int lane = tid & 63;
    const int wid  = tid >> 6;
    const int wr = wid >> 1, wc = wid & 1;
    const int lr = lane & 15, hi = lane >> 4;

    f32x4 acc[4][4];
    #pragma unroll
    for (int m = 0; m < 4; ++m)
        #pragma unroll
        for (int n = 0; n < 4; ++n) acc[m][n] = 0.f;

    for (int s = 0; s < KTOT24 / 64; ++s) {           // 5 steps of BK=64
        const int k0 = s * 64;
        #pragma unroll
        for (int i = 0; i < 4; ++i) {
            const int ub = (wid * 4 + i) * 64;        // wave-uniform base
            const int u  = ub + lane;                 // 16B unit 0..1023
            const int row = u >> 3;
            const int sw  = (((u & 7) ^ (row & 7))) * 8;   // swizzled src col
            int gr = rowbase + row;
            if (gr >= nrows) gr = nrows - 1;
            const ushort_t *ga, *gb;
            if (s == 0) {                             // K 0..63 = U2 | Ptrib
                ga = &U2b[(size_t)(gbase + gr) * T + q * CH + sw];
                gb = &Ptrib[(size_t)(colbase + row) * CH + sw];
            } else {                                  // K 64.. = Mq | Apb
                ga = &Mqb[((size_t)q * BD + gbase + gr) * ORD + (k0 - CH) + sw];
                gb = &Apb[(size_t)(colbase + row) * ORD + (k0 - CH) + sw];
            }
            gl_lds16(ga, &As[ub * 8]);
            gl_lds16(gb, &Bs[ub * 8]);
        }
        __syncthreads();
        #pragma unroll
        for (int t = 0; t < 2; ++t) {
            bf16x8 af[4], bfv[4];
            #pragma unroll
            for (int m = 0; m < 4; ++m) {
                int r = wr * 64 + m * 16 + lr;
                int un = (t * 4 + hi) ^ (r & 7);
                af[m] = *(const bf16x8*)&As[r * 64 + un * 8];
            }
            #pragma unroll
            for (int n = 0; n < 4; ++n) {
                int r = wc * 64 + n * 16 + lr;
                int un = (t * 4 + hi) ^ (r & 7);
                bfv[n] = *(const bf16x8*)&Bs[r * 64 + un * 8];
            }
            #pragma unroll
            for (int m = 0; m < 4; ++m)
                #pragma unroll
                for (int n = 0; n < 4; ++n)
                    acc[m][n] = __builtin_amdgcn_mfma_f32_16x16x32_bf16(af[m], bfv[n], acc[m][n], 0, 0, 0);
        }
        __syncthreads();
    }

    // ---- epilogue: acc -> LDS tile (aliases As/Bs) -> coalesced stores ----
    #pragma unroll
    for (int m = 0; m < 4; ++m)
        #pragma unroll
        for (int n = 0; n < 4; ++n)
            #pragma unroll
            for (int r = 0; r < 4; ++r)
                st[wr * 64 + m * 16 + hi * 4 + r]
                  [wc * 64 + n * 16 + lr] = f2bf(acc[m][n][r]);
    __syncthreads();

    const int c     = colbase >> 8;
    const int obase = colbase & 255;
    #pragma unroll
    for (int i = 0; i < 8; ++i) {
        int u  = tid + i * 256;
        int rl = u >> 4, cb = (u & 15) * 8;
        int grow = rowbase + rl;
        if (grow < nrows) {
            int bl = grow >> 3, d = grow & 7;
            size_t addr = ((size_t)(bl * T + q * CH + c)) * DO + (d << 8) + obase + cb;
            *(us8*)&mbuf[addr] = *(const us8*)&st[rl][cb];
        }
    }
}

// ====== MFMA GEMM 2: 256x256 tile, 8 waves, 64 ks-steps of K=32,
// 4 LDS slots/operand, 3-step prefetch, counted vmcnt(8) (T2+T3+T4+T5).
__global__ __launch_bounds__(512) void k_gemm5(const ushort_t* __restrict__ mbuf,
                                               const ushort_t* __restrict__ Whbt,
                                               const float* __restrict__ bh,
                                               float* __restrict__ out, int np) {
    __shared__ ushort_t A4[4][256 * 32];   // 4 slots x 16KB
    __shared__ ushort_t B4[4][256 * 32];   // 4 slots x 16KB -> 128KB total
    const int nwg = np * 2;
    int wg = blockIdx.x;
    int bx, by;
    if ((nwg & 7) == 0 && (np & 3) == 0) {
        int xcd = wg & 7, j = wg >> 3;
        bx = j & 1;
        by = xcd * (np >> 3) + (j >> 1);
    } else { bx = wg & 1; by = wg >> 1; }
    const int rowbase = by * 256;
    const int colbase = bx * 256;
    const int tid  = threadIdx.x;
    const int lane = tid & 63;
    const int wid  = tid >> 6;                 // 0..7
    const int wr = wid >> 2, wcw = wid & 3;    // 2 x 4 wave grid
    const int lr = lane & 15, hi = lane >> 4;

    f32x4 acc[8][4];
    #pragma unroll
    for (int m = 0; m < 8; ++m)
        #pragma unroll
        for (int n = 0; n < 4; ++n) acc[m][n] = 0.f;

    const int NT = DO / 32;                    // 64 ks-steps

    auto STAGE_A = [&](int s) {
        const int k0 = s * 32;
        ushort_t* slot = A4[s & 3];
        #pragma unroll
        for (int i = 0; i < 2; ++i) {
            const int ug = i * 512 + wid * 64;         // wave-uniform
            const int u  = ug + lane;                  // 0..1023
            const int row = u >> 2, uu = u & 3;
            const int col = k0 + ((uu ^ ((row >> 1) & 3)) * 8);
            gl_lds16(&mbuf[(size_t)(rowbase + row) * DO + col], &slot[ug * 8]);
        }
    };
    auto STAGE_B = [&](int s) {
        const int k0 = s * 32;
        ushort_t* slot = B4[s & 3];
        #pragma unroll
        for (int i = 0; i < 2; ++i) {
            const int ug = i * 512 + wid * 64;
            const int u  = ug + lane;
            const int row = u >> 2, uu = u & 3;
            const int col = k0 + ((uu ^ ((row >> 1) & 3)) * 8);
            gl_lds16(&Whbt[(size_t)(colbase + row) * DO + col], &slot[ug * 8]);
        }
    };

    STAGE_A(0); STAGE_B(0);
    STAGE_A(1); STAGE_B(1);
    STAGE_A(2); STAGE_B(2);
    asm volatile("s_waitcnt vmcnt(8)" ::: "memory");
    __builtin_amdgcn_s_barrier();

    for (int k = 0; k < NT; ++k) {
        const int sl = k & 3;
        ushort_t* As_ = A4[sl];
        ushort_t* Bs_ = B4[sl];
        bf16x8 bv[4], av[4];

        #pragma unroll
        for (int n = 0; n < 4; ++n) {
            int r = wcw * 64 + n * 16 + lr;
            bv[n] = *(const bf16x8*)&Bs_[r * 32 + ((hi ^ ((r >> 1) & 3)) * 8)];
        }
        #pragma unroll
        for (int m = 0; m < 4; ++m) {
            int r = wr * 128 + m * 16 + lr;
            av[m] = *(const bf16x8*)&As_[r * 32 + ((hi ^ ((r >> 1) & 3)) * 8)];
        }
        if (k + 3 < NT) STAGE_A(k + 3);
        __builtin_amdgcn_s_barrier();
        __builtin_amdgcn_s_setprio(1);
        #pragma unroll
        for (int m = 0; m < 4; ++m)
            #pragma unroll
            for (int n = 0; n < 4; ++n)
                acc[m][n] = __builtin_amdgcn_mfma_f32_16x16x32_bf16(av[m], bv[n], acc[m][n], 0, 0, 0);
        __builtin_amdgcn_s_setprio(0);

        #pragma unroll
        for (int m = 0; m < 4; ++m) {
            int r = wr * 128 + 64 + m * 16 + lr;
            av[m] = *(const bf16x8*)&As_[r * 32 + ((hi ^ ((r >> 1) & 3)) * 8)];
        }
        if (k + 3 < NT) STAGE_B(k + 3);
        __builtin_amdgcn_s_setprio(1);
        #pragma unroll
        for (int m = 0; m < 4; ++m)
            #pragma unroll
            for (int n = 0; n < 4; ++n)
                acc[4 + m][n] = __builtin_amdgcn_mfma_f32_16x16x32_bf16(av[m], bv[n], acc[4 + m][n], 0, 0, 0);
        __builtin_amdgcn_s_setprio(0);

        if (k < NT - 1) {
            if (k < NT - 3)       asm volatile("s_waitcnt vmcnt(8)" ::: "memory");
            else if (k == NT - 3) asm volatile("s_waitcnt vmcnt(4)" ::: "memory");
            else                  asm volatile("s_waitcnt vmcnt(0)" ::: "memory");
            __builtin_amdgcn_s_barrier();
        }
    }

    #pragma unroll
    for (int m = 0; m < 8; ++m) {
        #pragma unroll
        for (int n = 0; n < 4; ++n) {
            int col = colbase + wcw * 64 + n * 16 + lr;
            float bias = bh[col];
            #pragma unroll
            for (int r = 0; r < 4; ++r) {
                int grow = rowbase + wr * 128 + m * 16 + hi * 4 + r;
                out[(size_t)grow * HID + col] = tanhf(acc[m][n][r] + bias);
            }
        }
    }
}

// ---------------- launch ----------------
extern "C" void kernel_launch(void* const* d_in, const int* in_sizes, int n_in,
                              void* d_out, int out_size, void* d_ws, size_t ws_size,
                              hipStream_t stream) {
    const float* x    = (const float*)d_in[0];
    const float* kern = (const float*)d_in[1];
    const float* Wh   = (const float*)d_in[2];
    const float* bh   = (const float*)d_in[3];
    const float* A    = (const float*)d_in[4];
    const float* Brow = (const float*)d_in[5];
    float* out = (float*)d_out;

    char* base = (char*)d_ws;
    float*    U2    = (float*)(base + OFF_U2);
    float*    P     = (float*)(base + OFF_P);
    float*    Apow  = (float*)(base + OFF_APOW);
    float*    MqA   = (float*)(base + OFF_MQ);
    float*    Lend  = (float*)(base + OFF_LEND);
    ushort_t* U2b   = (ushort_t*)(base + OFF_U2B);
    ushort_t* Ptrib = (ushort_t*)(base + OFF_PTRB);
    ushort_t* Apb   = (ushort_t*)(base + OFF_APB);
    ushort_t* Whbt  = (ushort_t*)(base + OFF_WHBT);
    ushort_t* Mqb   = (ushort_t*)(base + OFF_MQB);
    ushort_t* mbuf  = (ushort_t*)(base + OFF_MBUF);

    float* A64  = Apow + (size_t)CH * OO;  // A^64 (slot 64)
    float* A128 = Apow;                    // Apow slot 0 (unused)
    float* A256 = U2;                      // U2 f32 dead after prep1
    float* A512 = U2 + OO;

    // choose largest batch group whose bf16 mbuf fits
    int G = 1;
    for (int g = 32; g >= 1; g >>= 1) {
        if (OFF_MBUF + (size_t)g * T * DO * 2 <= ws_size) { G = g; break; }
    }
    const int ngroups = BSZ / G;

    // fused independent prep: U proj + A copy/transpose + Wh transpose + P[0]
    k_prep0<<<dim3(2113), 256, 0, stream>>>(
        x, kern, U2, U2b, A, Apow, Apb, Wh, Whbt, Brow, P);

    // powers 2..64 by doubling + P-doubling rides along (K=128 bodies)
    for (int n = 1; n < CH; n <<= 1)
        k_pow_w<<<dim3(17 * n), 256, 0, stream>>>(Apow, Apb, P, n);

    // Ptrib build + chunk-end partials/scan-init (last use of U2 f32)
    k_prep1_w<<<dim3(512), 256, 0, stream>>>(P, Ptrib, U2, Lend, MqA);

    // Hillis-Steele matrix scan (f32), strides 1,2,4,8; passes 1-3 also
    // square Pw -> next power (blocks 256..271).
    k_scan_w<<<dim3(272), 256, 0, stream>>>(MqA, Lend, A64, 1, nullptr, A128);
    k_scan_w<<<dim3(272), 256, 0, stream>>>(Lend, MqA, A128, 2, nullptr, A256);
    k_scan_w<<<dim3(272), 256, 0, stream>>>(MqA, Lend, A256, 4, nullptr, A512);
    k_scan_w<<<dim3(256), 256, 0, stream>>>(Lend, MqA, A512, 8, Mqb, nullptr);

    // per batch-group: MFMA m-materialization + MFMA output GEMM
    for (int g = 0; g < ngroups; ++g) {
        const int gbase = g * G * MD;
        const int nrows = G * MD;
        const int gy24  = (nrows + 127) / 128;
        k_gemm24<<<dim3((CH * ORD) / 128, gy24, NQ), 256, 0, stream>>>(
            U2b, Mqb, Ptrib, Apb, mbuf, gbase, nrows);
        const int np = (G * T) / 256;          // 256-row panels
        k_gemm5<<<dim3(np * 2), 512, 0, stream>>>(
            mbuf, Whbt, bh, out + (size_t)g * G * T * HID, np);
    }
}